// Round 10
// baseline (383.877 us; speedup 1.0000x reference)
//
#include <hip/hip_runtime.h>

#define NN 50000
#define IN_DIM 128
#define HD 96
#define BN_EPS 1e-5f
#define PN_SCALE 20.0f
#define SCAN_NB 196   // ceil(50000/256)
#define CAP 64        // bucket capacity (Poisson(16): P(deg>=64) ~ 1e-17)

__device__ __forceinline__ float4 ld4(const float* p) { return *(const float4*)p; }
__device__ __forceinline__ float4 add4(float4 a, float4 b) {
    return make_float4(a.x + b.x, a.y + b.y, a.z + b.z, a.w + b.w);
}

// =================== tiled GEMM: C[N,96] = act(A[N,K]) @ W[96,K]^T + b ======
// LDS k-major layouts: As[k'][r] stride 68 (b128 row reads), Ws[k'][f] stride 98
// (3x b64 col reads). 64x96 tile, 256 threads, 4x6 acc.
// MODE 0: x -> h0; also zeroes cnt[] and stats[] (fused init).
// MODE 1: z -> h in place; fused BN colsum/colsumsq atomics.
// MODE 2: h -> l1 in place; BN scale/shift computed in prologue from raw stats
//         (fused bn_finalize); relu(a*scale+shift) on A; fused PN colsum + rowss.
template<int K, int MODE>
__global__ __launch_bounds__(256) void gemm_tiled(
    const float* A, const float* __restrict__ W, const float* __restrict__ bias,
    float* out,
    const float* __restrict__ gsum_in, const float* __restrict__ gsumsq_in,
    const float* __restrict__ gamma, const float* __restrict__ beta,
    float* __restrict__ gsum, float* __restrict__ gsumsq,
    float* __restrict__ gcol, float* __restrict__ growss,
    int* __restrict__ zero_cnt, float* __restrict__ zero_stats)
{
    constexpr int CK = 32;
    __shared__ __align__(16) float As[CK * 68];    // 2176 fl
    __shared__ __align__(16) float Ws[CK * 98];    // 3136 fl
    __shared__ float sc_sh[HD], sf_sh[HD];

    const int t  = threadIdx.x;
    const int tx = t & 15;        // cols tx*6 .. +5
    const int ty = t >> 4;        // rows ty*4 .. +3
    const int base = blockIdx.x * 64;

    if (MODE == 0) {
        // fused zeroing: each block zeroes its 64 cnt entries; blocks 0..3 zero stats
        int j = base + t % 64;
        if (t < 64 && j < NN) zero_cnt[j] = 0;
        if (blockIdx.x < 4) zero_stats[blockIdx.x * 256 + t] = 0.0f;
    }
    if (MODE == 2) {
        if (t < HD) {
            float mean = gsum_in[t] * (1.0f / NN);
            float var  = fmaxf(gsumsq_in[t] * (1.0f / NN) - mean * mean, 0.0f);
            float rstd = rsqrtf(var + BN_EPS);
            float sc = rstd * gamma[t];
            sc_sh[t] = sc;
            sf_sh[t] = beta[t] - mean * sc;
        }
        __syncthreads();
    }

    float acc[4][6];
#pragma unroll
    for (int i = 0; i < 4; ++i)
#pragma unroll
        for (int j = 0; j < 6; ++j) acc[i][j] = 0.0f;

    for (int kc = 0; kc < K; kc += CK) {
        // stage A (64 rows x 32 k) transposed: As[k'][r]
#pragma unroll
        for (int it = 0; it < 2; ++it) {
            int q = t + it * 256;
            int r = q >> 3, c4 = q & 7;
            int row = base + r;
            float4 v = make_float4(0.f, 0.f, 0.f, 0.f);
            if (row < NN) v = ld4(A + (size_t)row * K + kc + c4 * 4);
            if (MODE == 2) {
                int k0 = kc + c4 * 4;
                v.x = fmaxf(v.x * sc_sh[k0]     + sf_sh[k0],     0.f);
                v.y = fmaxf(v.y * sc_sh[k0 + 1] + sf_sh[k0 + 1], 0.f);
                v.z = fmaxf(v.z * sc_sh[k0 + 2] + sf_sh[k0 + 2], 0.f);
                v.w = fmaxf(v.w * sc_sh[k0 + 3] + sf_sh[k0 + 3], 0.f);
            }
            As[(c4 * 4 + 0) * 68 + r] = v.x;
            As[(c4 * 4 + 1) * 68 + r] = v.y;
            As[(c4 * 4 + 2) * 68 + r] = v.z;
            As[(c4 * 4 + 3) * 68 + r] = v.w;
        }
        // stage W (96 cols x 32 k) transposed: Ws[k'][f]
#pragma unroll
        for (int it = 0; it < 3; ++it) {
            int q = t + it * 256;
            int f = q >> 3, c4 = q & 7;
            float4 v = ld4(W + (size_t)f * K + kc + c4 * 4);
            Ws[(c4 * 4 + 0) * 98 + f] = v.x;
            Ws[(c4 * 4 + 1) * 98 + f] = v.y;
            Ws[(c4 * 4 + 2) * 98 + f] = v.z;
            Ws[(c4 * 4 + 3) * 98 + f] = v.w;
        }
        __syncthreads();
#pragma unroll
        for (int kk = 0; kk < CK; ++kk) {
            float4 a4 = *(const float4*)&As[kk * 68 + ty * 4];
            float2 b01 = *(const float2*)&Ws[kk * 98 + tx * 6];
            float2 b23 = *(const float2*)&Ws[kk * 98 + tx * 6 + 2];
            float2 b45 = *(const float2*)&Ws[kk * 98 + tx * 6 + 4];
            float a[4] = {a4.x, a4.y, a4.z, a4.w};
            float b[6] = {b01.x, b01.y, b23.x, b23.y, b45.x, b45.y};
#pragma unroll
            for (int i = 0; i < 4; ++i)
#pragma unroll
                for (int j = 0; j < 6; ++j) acc[i][j] += a[i] * b[j];
        }
        __syncthreads();
    }

    float cv[4][6];
#pragma unroll
    for (int j = 0; j < 6; ++j) {
        float bs = bias[tx * 6 + j];
#pragma unroll
        for (int i = 0; i < 4; ++i) cv[i][j] = acc[i][j] + bs;
    }
#pragma unroll
    for (int i = 0; i < 4; ++i) {
        int row = base + ty * 4 + i;
        if (row < NN) {
#pragma unroll
            for (int j = 0; j < 6; ++j)
                out[(size_t)row * HD + tx * 6 + j] = cv[i][j];
        }
    }

    if (MODE == 1) {
        float* rs_sum = As;            // [16][96]
        float* rs_sq  = Ws;            // [16][96]
        __syncthreads();
#pragma unroll
        for (int j = 0; j < 6; ++j) {
            float s = 0.f, q = 0.f;
#pragma unroll
            for (int i = 0; i < 4; ++i) {
                int row = base + ty * 4 + i;
                float v = (row < NN) ? cv[i][j] : 0.f;
                s += v; q += v * v;
            }
            rs_sum[ty * HD + tx * 6 + j] = s;
            rs_sq[ty * HD + tx * 6 + j]  = q;
        }
        __syncthreads();
        if (t < HD) {
            float S = 0.f, Q = 0.f;
#pragma unroll
            for (int r = 0; r < 16; ++r) { S += rs_sum[r * HD + t]; Q += rs_sq[r * HD + t]; }
            atomicAdd(&gsum[t], S);
            atomicAdd(&gsumsq[t], Q);
        }
    }

    if (MODE == 2) {
        float* rs_sum = As;            // [16][96]
        float* rr     = Ws;            // [64][16]
        __syncthreads();
#pragma unroll
        for (int j = 0; j < 6; ++j) {
            float s = 0.f;
#pragma unroll
            for (int i = 0; i < 4; ++i) {
                int row = base + ty * 4 + i;
                s += (row < NN) ? cv[i][j] : 0.f;
            }
            rs_sum[ty * HD + tx * 6 + j] = s;
        }
#pragma unroll
        for (int i = 0; i < 4; ++i) {
            float q = 0.f;
#pragma unroll
            for (int j = 0; j < 6; ++j) q += cv[i][j] * cv[i][j];
            rr[(ty * 4 + i) * 16 + tx] = q;
        }
        __syncthreads();
        if (t < HD) {
            float S = 0.f;
#pragma unroll
            for (int r = 0; r < 16; ++r) S += rs_sum[r * HD + t];
            atomicAdd(&gcol[t], S);
        }
        if (t < 64) {
            int row = base + t;
            if (row < NN) {
                float S = 0.f;
#pragma unroll
                for (int g = 0; g < 16; ++g) S += rr[t * 16 + g];
                growss[row] = S;
            }
        }
    }
}

// =================== bucket path (preferred) ===================
// fill directly into fixed 64-slot buckets; multipass dst-clustering for
// L2-resident write windows (~1.8 MB/pass).
__global__ __launch_bounds__(256) void fill_bucket(const int* __restrict__ ei,
                                                   int* __restrict__ cnt,
                                                   int* __restrict__ buckets, int E) {
    int t4 = blockIdx.x * 256 + threadIdx.x;
    int e0 = t4 * 4;
    int src[4], dst[4];
#pragma unroll
    for (int i = 0; i < 4; ++i) {
        int e = e0 + i;
        bool ok = e < E;
        dst[i] = ok ? ei[E + e] : -1;
        src[i] = ok ? ei[e] : 0;
    }
    for (int pass = 0; pass < 7; ++pass) {
#pragma unroll
        for (int i = 0; i < 4; ++i) {
            if (dst[i] >= 0 && (dst[i] >> 13) == pass) {
                int slot = atomicAdd(&cnt[dst[i]], 1);
                if (slot < CAP) buckets[dst[i] * CAP + slot] = src[i];
            }
        }
    }
}

// XCD-sliced gather: slice = blockIdx&7 -> 12 cols (3 float4); each XCD's L2
// only needs a 2.4 MB column slice of h0. 16 rows/block, 12 threads/row
// (3 cols x 4 edge groups), LDS combine.
__global__ __launch_bounds__(256) void gather_slice(
    const float* __restrict__ h0, const int* __restrict__ cnt,
    const int* __restrict__ buckets, float* __restrict__ z)
{
    __shared__ float4 red[192];
    const int t = threadIdx.x;
    const int s  = blockIdx.x & 7;      // col slice
    const int rb = blockIdx.x >> 3;     // row block
    float4 acc = make_float4(0.f, 0.f, 0.f, 0.f);
    int row = 0, g = 0, c = 0;
    if (t < 192) {
        const int rl = t / 12;
        const int w  = t - rl * 12;
        g = w / 3;                      // 0..3 edge group
        c = w - g * 3;                  // 0..2 col-f4 within slice
        row = rb * 16 + rl;
        const int fc = (s * 3 + c) * 4; // feature col base
        const int n = min(cnt[row], CAP);
        const int b0 = row * CAP;
        int q0 = (n * g) / 4;
        int q1 = (n * (g + 1)) / 4;
        if (g == 0) acc = ld4(h0 + (size_t)row * HD + fc);
        int p = q0;
        for (; p + 4 <= q1; p += 4) {
            int s0 = buckets[b0 + p],     s1 = buckets[b0 + p + 1];
            int s2 = buckets[b0 + p + 2], s3 = buckets[b0 + p + 3];
            float4 v0 = ld4(h0 + (size_t)s0 * HD + fc);
            float4 v1 = ld4(h0 + (size_t)s1 * HD + fc);
            float4 v2 = ld4(h0 + (size_t)s2 * HD + fc);
            float4 v3 = ld4(h0 + (size_t)s3 * HD + fc);
            acc = add4(acc, add4(add4(v0, v1), add4(v2, v3)));
        }
        for (; p < q1; ++p)
            acc = add4(acc, ld4(h0 + (size_t)buckets[b0 + p] * HD + fc));
        red[t] = acc;
    }
    __syncthreads();
    if (t < 192 && g == 0) {
        acc = add4(add4(acc, red[t + 3]), add4(red[t + 6], red[t + 9]));
        *(float4*)(z + (size_t)row * HD + (s * 3 + c) * 4) = acc;
    }
}

// =================== CSR fallback path ===================
__global__ void hist_kernel(const int* __restrict__ ei, int* __restrict__ cnt, int E) {
    int e = blockIdx.x * blockDim.x + threadIdx.x;
    if (e < E) atomicAdd(&cnt[ei[E + e]], 1);
}

__global__ __launch_bounds__(256) void scan_part1(const int* __restrict__ cnt,
                                                  int* __restrict__ bsum) {
    __shared__ int sh[256];
    int i = blockIdx.x * 256 + threadIdx.x;
    int t = threadIdx.x;
    sh[t] = (i < NN) ? cnt[i] : 0;
    __syncthreads();
    for (int off = 128; off > 0; off >>= 1) {
        if (t < off) sh[t] += sh[t + off];
        __syncthreads();
    }
    if (t == 0) bsum[blockIdx.x] = sh[0];
}

__global__ __launch_bounds__(256) void scan_part2(int* __restrict__ bsum) {
    __shared__ int sh[256];
    int t = threadIdx.x;
    int v = (t < SCAN_NB) ? bsum[t] : 0;
    sh[t] = v;
    __syncthreads();
    for (int off = 1; off < 256; off <<= 1) {
        int u = sh[t];
        if (t >= off) u += sh[t - off];
        __syncthreads();
        sh[t] = u;
        __syncthreads();
    }
    if (t < SCAN_NB) bsum[t] = sh[t] - v;
}

__global__ __launch_bounds__(256) void scan_part3(int* __restrict__ cnt,
                                                  const int* __restrict__ bsum,
                                                  int* __restrict__ rowptr) {
    __shared__ int sh[256];
    int i = blockIdx.x * 256 + threadIdx.x;
    int t = threadIdx.x;
    int v = (i < NN) ? cnt[i] : 0;
    sh[t] = v;
    __syncthreads();
    for (int off = 1; off < 256; off <<= 1) {
        int u = sh[t];
        if (t >= off) u += sh[t - off];
        __syncthreads();
        sh[t] = u;
        __syncthreads();
    }
    int excl = sh[t] - v + bsum[blockIdx.x];
    if (i < NN) { rowptr[i] = excl; cnt[i] = excl; }
    if (i == NN - 1) rowptr[NN] = excl + v;
}

__global__ __launch_bounds__(256) void fill_csr(const int* __restrict__ ei,
                                                int* __restrict__ cursor,
                                                int* __restrict__ srcs, int E) {
    int t4 = blockIdx.x * 256 + threadIdx.x;
    int e0 = t4 * 4;
    int src[4], dst[4];
#pragma unroll
    for (int i = 0; i < 4; ++i) {
        int e = e0 + i;
        bool ok = e < E;
        dst[i] = ok ? ei[E + e] : -1;
        src[i] = ok ? ei[e] : 0;
    }
    for (int pass = 0; pass < 7; ++pass) {
#pragma unroll
        for (int i = 0; i < 4; ++i) {
            if (dst[i] >= 0 && (dst[i] >> 13) == pass) {
                int slot = atomicAdd(&cursor[dst[i]], 1);
                srcs[slot] = src[i];
            }
        }
    }
}

__global__ __launch_bounds__(768) void gather_csr(
    const float* __restrict__ h0, const int* __restrict__ rowptr,
    const int* __restrict__ srcs, float* __restrict__ z)
{
    __shared__ float4 red[768];
    const int tid = threadIdx.x;
    const int rl  = tid / 96;
    const int wi  = tid - rl * 96;
    const int g   = wi / 24;
    const int c   = wi - g * 24;
    const int row = blockIdx.x * 8 + rl;

    const int p0 = rowptr[row];
    const int cnt = rowptr[row + 1] - p0;
    int q0 = p0 + (cnt * g) / 4;
    int q1 = p0 + (cnt * (g + 1)) / 4;

    float4 acc = (g == 0) ? ld4(h0 + (size_t)row * HD + c * 4)
                          : make_float4(0.f, 0.f, 0.f, 0.f);
    int p = q0;
    for (; p + 4 <= q1; p += 4) {
        int s0 = srcs[p], s1 = srcs[p + 1], s2 = srcs[p + 2], s3 = srcs[p + 3];
        acc = add4(acc, add4(add4(ld4(h0 + (size_t)s0 * HD + c * 4),
                                  ld4(h0 + (size_t)s1 * HD + c * 4)),
                             add4(ld4(h0 + (size_t)s2 * HD + c * 4),
                                  ld4(h0 + (size_t)s3 * HD + c * 4))));
    }
    for (; p < q1; ++p)
        acc = add4(acc, ld4(h0 + (size_t)srcs[p] * HD + c * 4));

    red[tid] = acc;
    __syncthreads();
    if (g == 0) {
        acc = add4(add4(acc, red[tid + 24]), add4(red[tid + 48], red[tid + 72]));
        *(float4*)(z + (size_t)row * HD + c * 4) = acc;
    }
}

// ---------------- PairNorm: streaming float4, in place ----------------
__global__ __launch_bounds__(256) void pn_kernel(float* l1, const float* __restrict__ colsum,
                                                 const float* __restrict__ rowss)
{
    int idx = blockIdx.x * 256 + threadIdx.x;
    if (idx >= NN * 24) return;
    int row = idx / 24;
    int q = idx - row * 24;
    float rs = rsqrtf(1e-6f + rowss[row]);
    float4 v = ld4(l1 + (size_t)idx * 4);
    float4 cm = ld4(colsum + q * 4);
    v.x = PN_SCALE * v.x * rs - cm.x * (1.0f / NN);
    v.y = PN_SCALE * v.y * rs - cm.y * (1.0f / NN);
    v.z = PN_SCALE * v.z * rs - cm.z * (1.0f / NN);
    v.w = PN_SCALE * v.w * rs - cm.w * (1.0f / NN);
    *(float4*)(l1 + (size_t)idx * 4) = v;
}

extern "C" void kernel_launch(void* const* d_in, const int* in_sizes, int n_in,
                              void* d_out, int out_size, void* d_ws, size_t ws_size,
                              hipStream_t stream) {
    const float* x     = (const float*)d_in[0];
    const int*   ei    = (const int*)d_in[1];
    const float* W0    = (const float*)d_in[2];
    const float* b0    = (const float*)d_in[3];
    const float* W1    = (const float*)d_in[4];
    const float* b1    = (const float*)d_in[5];
    const float* gamma = (const float*)d_in[6];
    const float* beta  = (const float*)d_in[7];
    const float* W2    = (const float*)d_in[8];
    const float* b2    = (const float*)d_in[9];

    float* out_l1 = (float*)d_out;                 // [N,96]: z -> h -> l1 (in place)
    float* out_h0 = out_l1 + (size_t)NN * HD;      // [N,96]: h0 output

    // ws layout: stats 1024 fl | rowss NN fl | cnt NN int | then per-path
    float* stats   = (float*)d_ws;
    float* s_sum   = stats;            // 96
    float* s_sumsq = stats + HD;       // 96
    float* s_col   = stats + 2 * HD;   // 96
    float* rowss = stats + 1024;
    int* cnt = (int*)(rowss + NN);
    int* pathmem = cnt + NN;

    const int E = in_sizes[1] / 2;                 // 800000
    const int GB = (NN + 63) / 64;                 // 782

    size_t base_bytes = (1024 + NN) * 4 + NN * 4;
    bool bucket_ok = ws_size >= base_bytes + (size_t)NN * CAP * 4;

    // 1) h0 = x @ W0^T + b0  (+ fused zeroing of cnt/stats)
    gemm_tiled<IN_DIM, 0><<<GB, 256, 0, stream>>>(x, W0, b0, out_h0,
        nullptr, nullptr, nullptr, nullptr, nullptr, nullptr, nullptr, nullptr,
        cnt, stats);

    if (bucket_ok) {
        int* buckets = pathmem;                    // NN*64 int = 12.8 MB
        fill_bucket<<<(E / 4 + 255) / 256, 256, 0, stream>>>(ei, cnt, buckets, E);
        gather_slice<<<8 * (NN / 16), 256, 0, stream>>>(out_h0, cnt, buckets, out_l1);
    } else {
        int* rowptr = pathmem;                     // NN+2
        int* bsum   = rowptr + NN + 2;             // 256
        int* srcs   = bsum + 256;                  // E
        hist_kernel<<<(E + 255) / 256, 256, 0, stream>>>(ei, cnt, E);
        scan_part1<<<SCAN_NB, 256, 0, stream>>>(cnt, bsum);
        scan_part2<<<1, 256, 0, stream>>>(bsum);
        scan_part3<<<SCAN_NB, 256, 0, stream>>>(cnt, bsum, rowptr);
        fill_csr<<<(E / 4 + 255) / 256, 256, 0, stream>>>(ei, cnt, srcs, E);
        gather_csr<<<NN / 8, 768, 0, stream>>>(out_h0, rowptr, srcs, out_l1);
    }

    // 2) h = z @ W1^T + b1 (in place) + fused BN stats
    gemm_tiled<HD, 1><<<GB, 256, 0, stream>>>(out_l1, W1, b1, out_l1,
        nullptr, nullptr, nullptr, nullptr, s_sum, s_sumsq, nullptr, nullptr,
        nullptr, nullptr);
    // 3) l1 = relu(bn(h)) @ W2^T + b2 (in place) + fused bn_finalize + PN stats
    gemm_tiled<HD, 2><<<GB, 256, 0, stream>>>(out_l1, W2, b2, out_l1,
        s_sum, s_sumsq, gamma, beta, nullptr, nullptr, s_col, rowss,
        nullptr, nullptr);
    // 4) PairNorm finalize (streaming, in place)
    pn_kernel<<<(NN * 24 + 255) / 256, 256, 0, stream>>>(out_l1, s_col, rowss);
}